// Round 3
// baseline (273.607 us; speedup 1.0000x reference)
//
#include <hip/hip_runtime.h>

// YOLOv1 loss: 802816 rows x 30 f32, two tensors, scalar out.
// R3: K1 processes 2 rows/thread (240B = 15 float4, 16B-aligned) with ALL
// 30 float4 loads batched before use; __launch_bounds__(256,2) raises the
// VGPR budget so the scheduler hoists the full batch (R2's VGPR=24 showed
// it was serializing loads for occupancy's sake -> latency-bound 2.5 TB/s).

#define COLS 30
#define RPB  512               // rows per K1 block (256 thr x 2 rows)
#define NB   1568              // 802816 / 512

// Per-row loss math (bit-exact vs reference; constant indices after inline).
__device__ __forceinline__ void row_compute(const float* __restrict__ P,
                                            const float* __restrict__ T,
                                            bool& coord, float& r, float& noo) {
    const float C = 1.0f / 7.0f;
    float conf = T[4];
    coord = (conf == 1.0f);          // targets col 4 is exactly 0.0 / 1.0
    noo = 0.0f;
    if (conf == 0.0f) {
        float d4 = P[4] - conf;      // t4 == 0 here
        float d9 = P[9] - T[9];
        noo = d4 * d4 + d9 * d9;
    }
    float t0 = T[0], t1 = T[1], t2 = T[2], t3 = T[3];
    float tb0 = t0 * t0, tb1 = t1 * t1, tb2 = t2 * t2, tb3 = t3 * t3;
    float tax = tb0 * C - tb2, tay = tb1 * C - tb3;
    float tbx = tax * C + tb2, tby = tay * C + tb3;
    float areaT = (tbx - tax) * (tby - tay);
    float iou0 = 0.0f, iou1 = 0.0f;
#pragma unroll
    for (int b = 0; b < 2; ++b) {
        float px = P[5 * b + 0], py = P[5 * b + 1];
        float pw = P[5 * b + 2], ph = P[5 * b + 3];
        float pax = px * C - pw, pay = py * C - ph;
        float pbx = pax * C + pw, pby = pay * C + ph;
        float ltx = fmaxf(pax, tax), lty = fmaxf(pay, tay);
        float rbx = fminf(pbx, tbx), rby = fminf(pby, tby);
        float wx = fmaxf(rbx - ltx, 0.0f), wy = fmaxf(rby - lty, 0.0f);
        float inter = wx * wy;
        float areaP = (pbx - pax) * (pby - pay);
        float iou = inter / (areaP + areaT - inter);
        if (b == 0) iou0 = iou; else iou1 = iou;
    }
    int idx = (iou1 > iou0) ? 1 : 0;         // argmax, first on ties
    float sx = idx ? P[5] : P[0];
    float sy = idx ? P[6] : P[1];
    float sw = idx ? P[7] : P[2];
    float sh = idx ? P[8] : P[3];
    float best = T[10]; float pc = P[10];    // class argmax, strict >
#pragma unroll
    for (int j = 1; j < 20; ++j) {
        float v = T[10 + j];
        if (v > best) { best = v; pc = P[10 + j]; }
    }
    float d0 = sx - t0, d1 = sy - t1, d2 = sw - t2, d3 = sh - t3;
    float dc = pc - 1.0f;
    r = d0 * d0 + d1 * d1 + d2 * d2 + d3 * d3 + 2.0f * dc * dc;
}

// Load a 2-row chunk (60 floats, 240B, 16B-aligned) as 15 batched float4s.
__device__ __forceinline__ void load_pair(const float* __restrict__ src,
                                          long pair, float* dst) {
    const float4* s4 = (const float4*)(src + pair * (long)(2 * COLS));
    float4 v[15];
#pragma unroll
    for (int i = 0; i < 15; ++i) v[i] = s4[i];
#pragma unroll
    for (int i = 0; i < 15; ++i) {
        dst[4 * i + 0] = v[i].x; dst[4 * i + 1] = v[i].y;
        dst[4 * i + 2] = v[i].z; dst[4 * i + 3] = v[i].w;
    }
}

// Both tensors' pair-chunks with all 30 float4 loads issued back-to-back.
__device__ __forceinline__ void load_pair2(const float* __restrict__ p,
                                           const float* __restrict__ t,
                                           long pair, float* cp, float* ct) {
    const float4* p4 = (const float4*)(p + pair * (long)(2 * COLS));
    const float4* t4 = (const float4*)(t + pair * (long)(2 * COLS));
    float4 a[15], b[15];
#pragma unroll
    for (int i = 0; i < 15; ++i) a[i] = p4[i];
#pragma unroll
    for (int i = 0; i < 15; ++i) b[i] = t4[i];
#pragma unroll
    for (int i = 0; i < 15; ++i) {
        cp[4 * i + 0] = a[i].x; cp[4 * i + 1] = a[i].y;
        cp[4 * i + 2] = a[i].z; cp[4 * i + 3] = a[i].w;
        ct[4 * i + 0] = b[i].x; ct[4 * i + 1] = b[i].y;
        ct[4 * i + 2] = b[i].z; ct[4 * i + 3] = b[i].w;
    }
}

// K1: per-block (512 rows) {coord count, sum of coord r-terms, noobj sum}
__global__ __launch_bounds__(256, 2) void yolo_k1(const float* __restrict__ p,
                                                  const float* __restrict__ t,
                                                  int* __restrict__ cnt,
                                                  float* __restrict__ sumR,
                                                  float* __restrict__ noo) {
    __shared__ float wr[4], wn[4];
    __shared__ int wc[4];
    int tid = threadIdx.x;
    long pair = (long)blockIdx.x * 256 + tid;
    float cp[60], ct[60];
    load_pair2(p, t, pair, cp, ct);

    bool cA, cB; float rA, rB, nA, nB;
    row_compute(cp, ct, cA, rA, nA);
    row_compute(cp + 30, ct + 30, cB, rB, nB);
    float rl = (cA ? rA : 0.0f) + (cB ? rB : 0.0f);
    float nt = nA + nB;
    int c = (cA ? 1 : 0) + (cB ? 1 : 0);

#pragma unroll
    for (int off = 32; off > 0; off >>= 1) {
        rl += __shfl_down(rl, off);
        nt += __shfl_down(nt, off);
        c  += __shfl_down(c, off);
    }
    int wave = tid >> 6, lane = tid & 63;
    if (lane == 0) { wr[wave] = rl; wn[wave] = nt; wc[wave] = c; }
    __syncthreads();
    if (tid == 0) {
        cnt[blockIdx.x]  = wc[0] + wc[1] + wc[2] + wc[3];
        sumR[blockIdx.x] = wr[0] + wr[1] + wr[2] + wr[3];
        noo[blockIdx.x]  = wn[0] + wn[1] + wn[2] + wn[3];
    }
}

// K2: totals + scan + boundary-block (512 rows) fixup, single block.
__global__ __launch_bounds__(256) void yolo_k2(const int* __restrict__ cnt,
                                               const float* __restrict__ sumR,
                                               const float* __restrict__ noo,
                                               const float* __restrict__ p,
                                               const float* __restrict__ t,
                                               float* __restrict__ out) {
    __shared__ int   wsum[4];
    __shared__ float wf[4], wn2[4];
    __shared__ int   s_bstar, s_kstar;
    __shared__ float s_base;
    __shared__ int   s_wcnt[4];
    int tid = threadIdx.x;
    int lane = tid & 63, wave = tid >> 6;
    if (tid == 0) { s_bstar = -1; s_kstar = 0; }

    const int PER = 7;                  // 256*7 = 1792 >= 1568
    int start = tid * PER;
    int end = min(NB, start + PER);

    int cloc = 0; float nloc = 0.0f;
    for (int i = start; i < end; ++i) { cloc += cnt[i]; nloc += noo[i]; }

    int incl = cloc;                    // inclusive shfl scan within wave
#pragma unroll
    for (int off = 1; off < 64; off <<= 1) {
        int v = __shfl_up(incl, off);
        if (lane >= off) incl += v;
    }
    if (lane == 63) wsum[wave] = incl;
    __syncthreads();
    int woff = 0;
#pragma unroll
    for (int w = 0; w < 4; ++w) woff += (w < wave) ? wsum[w] : 0;
    int ex = woff + incl - cloc;        // exclusive global prefix
    int n_obj = wsum[0] + wsum[1] + wsum[2] + wsum[3];
    int n_half = n_obj >> 1;

    float acc = 0.0f;
    int running = ex;
    for (int i = start; i < end; ++i) {
        int ci = cnt[i];
        if (ci > 0) {
            if (running + ci <= n_half) {
                acc += sumR[i];
            } else if (running < n_half) {  // exactly one thread ever
                s_bstar = i;
                s_kstar = n_half - running;
            }
        }
        running += ci;
    }

#pragma unroll
    for (int off = 32; off > 0; off >>= 1) {
        acc  += __shfl_down(acc, off);
        nloc += __shfl_down(nloc, off);
    }
    if (lane == 0) { wf[wave] = acc; wn2[wave] = nloc; }
    __syncthreads();
    if (tid == 0)
        s_base = 5.0f * (wf[0] + wf[1] + wf[2] + wf[3])
               + 0.5f * (wn2[0] + wn2[1] + wn2[2] + wn2[3]);
    __syncthreads();

    // Phase B: boundary block (512 rows, 2 rows/thread, interleaved ranks)
    int bstar = s_bstar, kstar = s_kstar;
    float total = 0.0f;
    if (bstar >= 0) {                    // uniform branch
        long pair = (long)bstar * 256 + tid;
        float cp[60], ctt[60];
        load_pair2(p, t, pair, cp, ctt);
        bool cA, cB; float rA, rB, nA2, nB2;
        row_compute(cp, ctt, cA, rA, nA2);
        row_compute(cp + 30, ctt + 30, cB, rB, nB2);
        unsigned long long balA = __ballot(cA);
        unsigned long long balB = __ballot(cB);
        if (lane == 0)
            s_wcnt[wave] = (int)__popcll(balA) + (int)__popcll(balB);
        __syncthreads();
        int waveoff = 0;
#pragma unroll
        for (int w = 0; w < 4; ++w) waveoff += (w < wave) ? s_wcnt[w] : 0;
        unsigned long long lemask =
            (lane == 63) ? ~0ull : ((1ull << (lane + 1)) - 1ull);
        unsigned long long ltmask = (1ull << lane) - 1ull;
        // rows interleave: lane l covers global rows 2l (A) and 2l+1 (B)
        int rankA = waveoff + (int)__popcll(balA & lemask)
                            + (int)__popcll(balB & ltmask);
        int rankB = waveoff + (int)__popcll(balA & lemask)
                            + (int)__popcll(balB & lemask);
        float val = ((cA && rankA <= kstar) ? rA : 0.0f)
                  + ((cB && rankB <= kstar) ? rB : 0.0f);
#pragma unroll
        for (int off = 32; off > 0; off >>= 1) val += __shfl_down(val, off);
        if (lane == 0) wf[wave] = val;
        __syncthreads();
        if (tid == 0) total = wf[0] + wf[1] + wf[2] + wf[3];
    }
    if (tid == 0) out[0] = s_base + 5.0f * total;
}

extern "C" void kernel_launch(void* const* d_in, const int* in_sizes, int n_in,
                              void* d_out, int out_size, void* d_ws, size_t ws_size,
                              hipStream_t stream) {
    (void)in_sizes; (void)n_in; (void)out_size; (void)ws_size;
    const float* p = (const float*)d_in[0];   // predictions
    const float* t = (const float*)d_in[1];   // targets
    char* ws = (char*)d_ws;                   // ~19 KB used
    int*   cnt  = (int*)ws;
    float* sumR = (float*)(ws + (size_t)NB * 4);
    float* noo  = (float*)(ws + (size_t)NB * 8);
    float* out  = (float*)d_out;

    yolo_k1<<<NB, 256, 0, stream>>>(p, t, cnt, sumR, noo);
    yolo_k2<<<1, 256, 0, stream>>>(cnt, sumR, noo, p, t, out);
}

// Round 4
// 215.824 us; speedup vs baseline: 1.2677x; 1.2677x over previous
//
#include <hip/hip_runtime.h>

// YOLOv1 loss: 802816 rows x 30 f32, two tensors, scalar out.
// R4: R2/R3 post-mortem showed local arrays (float[30]/float[60]) were
// lowered to SCRATCH (VGPR_Count 24/36 << live values) -> every row made an
// HBM round-trip through private memory; kernels were scratch-latency-bound
// at ~2.2-2.5 TB/s. This version has NO local arrays: all 30 float2 per
// tensor-row live in named scalars, math folded onto the names.
// __launch_bounds__(256,4) -> 128-VGPR budget, 16 waves/CU, ~15 KB of
// loads in flight per wave.

#define COLS 30
#define NB   3136              // 802816 rows / 256 rows per K1 block

// Load one row of both tensors (15 float2 each, rows are 120 B / 8 B
// aligned) into named registers and compute the per-row terms. Bit-exact
// vs the reference. No arrays -> no scratch.
__device__ __forceinline__ void row_load_compute(
    const float* __restrict__ gp, const float* __restrict__ gt, long row,
    bool& coord, float& r, float& noo)
{
    const float2* P2 = (const float2*)(gp + row * (long)COLS);
    const float2* T2 = (const float2*)(gt + row * (long)COLS);
    // predictions P[0..29]
    float2 a0 = P2[0],  a1 = P2[1],  a2 = P2[2],  a3 = P2[3],  a4 = P2[4];
    float2 a5 = P2[5],  a6 = P2[6],  a7 = P2[7],  a8 = P2[8],  a9 = P2[9];
    float2 a10 = P2[10], a11 = P2[11], a12 = P2[12], a13 = P2[13], a14 = P2[14];
    // targets T[0..29]
    float2 b0 = T2[0],  b1 = T2[1],  b2 = T2[2],  b3 = T2[3],  b4 = T2[4];
    float2 b5 = T2[5],  b6 = T2[6],  b7 = T2[7],  b8 = T2[8],  b9 = T2[9];
    float2 b10 = T2[10], b11 = T2[11], b12 = T2[12], b13 = T2[13], b14 = T2[14];

    const float C = 1.0f / 7.0f;
    float conf = b2.x;                    // T[4], exactly 0.0 or 1.0
    coord = (conf == 1.0f);
    noo = 0.0f;
    if (conf == 0.0f) {
        float d4 = a2.x - conf;           // P[4] - T[4] (T[4]==0 here)
        float d9 = a4.y - b4.y;           // P[9] - T[9]
        noo = d4 * d4 + d9 * d9;
    }
    // target box (T[0..3] squared)
    float T0 = b0.x, T1 = b0.y, T2v = b1.x, T3 = b1.y;
    float tb0 = T0 * T0, tb1 = T1 * T1, tb2 = T2v * T2v, tb3 = T3 * T3;
    float tax = tb0 * C - tb2, tay = tb1 * C - tb3;
    float tbx = tax * C + tb2, tby = tay * C + tb3;
    float areaT = (tbx - tax) * (tby - tay);
    // pred box 0: P[0..3] = a0.x a0.y a1.x a1.y
    float pax0 = a0.x * C - a1.x, pay0 = a0.y * C - a1.y;
    float pbx0 = pax0 * C + a1.x, pby0 = pay0 * C + a1.y;
    // pred box 1: P[5..8] = a2.y a3.x a3.y a4.x
    float pax1 = a2.y * C - a3.y, pay1 = a3.x * C - a4.x;
    float pbx1 = pax1 * C + a3.y, pby1 = pay1 * C + a4.x;
    // IoU box 0
    float ltx = fmaxf(pax0, tax), lty = fmaxf(pay0, tay);
    float rbx = fminf(pbx0, tbx), rby = fminf(pby0, tby);
    float wx = fmaxf(rbx - ltx, 0.0f), wy = fmaxf(rby - lty, 0.0f);
    float inter = wx * wy;
    float areaP = (pbx0 - pax0) * (pby0 - pay0);
    float iou0 = inter / (areaP + areaT - inter);
    // IoU box 1
    ltx = fmaxf(pax1, tax); lty = fmaxf(pay1, tay);
    rbx = fminf(pbx1, tbx); rby = fminf(pby1, tby);
    wx = fmaxf(rbx - ltx, 0.0f); wy = fmaxf(rby - lty, 0.0f);
    inter = wx * wy;
    areaP = (pbx1 - pax1) * (pby1 - pay1);
    float iou1 = inter / (areaP + areaT - inter);

    int idx = (iou1 > iou0) ? 1 : 0;      // argmax, first on ties
    float sx = idx ? a2.y : a0.x;
    float sy = idx ? a3.x : a0.y;
    float sw = idx ? a3.y : a1.x;
    float sh = idx ? a4.x : a1.y;
    // class argmax over T[10..29] (strict > => first occurrence), track pc
    float best = b5.x, pc = a5.x;
#define CLS_STEP(tv, pv) { float v_ = (tv); if (v_ > best) { best = v_; pc = (pv); } }
    CLS_STEP(b5.y,  a5.y)  CLS_STEP(b6.x,  a6.x)  CLS_STEP(b6.y,  a6.y)
    CLS_STEP(b7.x,  a7.x)  CLS_STEP(b7.y,  a7.y)  CLS_STEP(b8.x,  a8.x)
    CLS_STEP(b8.y,  a8.y)  CLS_STEP(b9.x,  a9.x)  CLS_STEP(b9.y,  a9.y)
    CLS_STEP(b10.x, a10.x) CLS_STEP(b10.y, a10.y) CLS_STEP(b11.x, a11.x)
    CLS_STEP(b11.y, a11.y) CLS_STEP(b12.x, a12.x) CLS_STEP(b12.y, a12.y)
    CLS_STEP(b13.x, a13.x) CLS_STEP(b13.y, a13.y) CLS_STEP(b14.x, a14.x)
    CLS_STEP(b14.y, a14.y)
#undef CLS_STEP
    float d0 = sx - T0, d1 = sy - T1, d2 = sw - T2v, d3 = sh - T3;
    float dc = pc - 1.0f;
    r = d0 * d0 + d1 * d1 + d2 * d2 + d3 * d3 + 2.0f * dc * dc;
}

// K1: per-block (256 rows) {coord count, sum of coord r-terms, noobj sum}
__global__ __launch_bounds__(256, 4) void yolo_k1(const float* __restrict__ gp,
                                                  const float* __restrict__ gt,
                                                  int* __restrict__ cnt,
                                                  float* __restrict__ sumR,
                                                  float* __restrict__ noo) {
    __shared__ float wr[4], wn[4];
    __shared__ int wc[4];
    int tid = threadIdx.x;
    long row = (long)blockIdx.x * 256 + tid;
    bool coord; float r, nt;
    row_load_compute(gp, gt, row, coord, r, nt);
    float rl = coord ? r : 0.0f;

    unsigned long long bal = __ballot(coord);
    int c = (int)__popcll(bal);
#pragma unroll
    for (int off = 32; off > 0; off >>= 1) {
        rl += __shfl_down(rl, off);
        nt += __shfl_down(nt, off);
    }
    int wave = tid >> 6, lane = tid & 63;
    if (lane == 0) { wr[wave] = rl; wn[wave] = nt; wc[wave] = c; }
    __syncthreads();
    if (tid == 0) {
        cnt[blockIdx.x]  = wc[0] + wc[1] + wc[2] + wc[3];
        sumR[blockIdx.x] = wr[0] + wr[1] + wr[2] + wr[3];
        noo[blockIdx.x]  = wn[0] + wn[1] + wn[2] + wn[3];
    }
}

// K2: totals + scan + boundary-block fixup, single block, 2-phase.
__global__ __launch_bounds__(256) void yolo_k2(const int* __restrict__ cnt,
                                               const float* __restrict__ sumR,
                                               const float* __restrict__ noo,
                                               const float* __restrict__ gp,
                                               const float* __restrict__ gt,
                                               float* __restrict__ out) {
    __shared__ int   wsum[4];
    __shared__ float wf[4], wn2[4];
    __shared__ int   s_bstar, s_kstar;
    __shared__ float s_base;
    __shared__ int   s_wcnt[4];
    int tid = threadIdx.x;
    int lane = tid & 63, wave = tid >> 6;
    if (tid == 0) { s_bstar = -1; s_kstar = 0; }

    const int PER = 13;                 // 256*13 = 3328 >= 3136
    int start = tid * PER;
    int end = min(NB, start + PER);

    int cloc = 0; float nloc = 0.0f;
    for (int i = start; i < end; ++i) { cloc += cnt[i]; nloc += noo[i]; }

    int incl = cloc;                    // inclusive shfl scan within wave
#pragma unroll
    for (int off = 1; off < 64; off <<= 1) {
        int v = __shfl_up(incl, off);
        if (lane >= off) incl += v;
    }
    if (lane == 63) wsum[wave] = incl;
    __syncthreads();                    // also orders s_bstar init vs walk
    int woff = 0;
#pragma unroll
    for (int w = 0; w < 4; ++w) woff += (w < wave) ? wsum[w] : 0;
    int ex = woff + incl - cloc;        // exclusive global prefix
    int n_obj = wsum[0] + wsum[1] + wsum[2] + wsum[3];
    int n_half = n_obj >> 1;

    float acc = 0.0f;
    int running = ex;
    for (int i = start; i < end; ++i) {
        int ci = cnt[i];
        if (ci > 0) {
            if (running + ci <= n_half) {
                acc += sumR[i];
            } else if (running < n_half) {  // exactly one thread ever
                s_bstar = i;
                s_kstar = n_half - running;
            }
        }
        running += ci;
    }

#pragma unroll
    for (int off = 32; off > 0; off >>= 1) {
        acc  += __shfl_down(acc, off);
        nloc += __shfl_down(nloc, off);
    }
    if (lane == 0) { wf[wave] = acc; wn2[wave] = nloc; }
    __syncthreads();
    if (tid == 0)
        s_base = 5.0f * (wf[0] + wf[1] + wf[2] + wf[3])
               + 0.5f * (wn2[0] + wn2[1] + wn2[2] + wn2[3]);
    __syncthreads();

    // Phase B: boundary block fixup (256 rows)
    int bstar = s_bstar, kstar = s_kstar;
    float total = 0.0f;
    if (bstar >= 0) {                    // uniform branch
        long row = (long)bstar * 256 + tid;
        bool coord; float r, nt;
        row_load_compute(gp, gt, row, coord, r, nt);
        unsigned long long bal = __ballot(coord);
        if (lane == 0) s_wcnt[wave] = (int)__popcll(bal);
        __syncthreads();
        int waveoff = 0;
#pragma unroll
        for (int w = 0; w < 4; ++w) waveoff += (w < wave) ? s_wcnt[w] : 0;
        unsigned long long below_incl =
            (lane == 63) ? bal : (bal & ((1ull << (lane + 1)) - 1ull));
        int rank = waveoff + (int)__popcll(below_incl);  // inclusive rank
        float val = (coord && rank <= kstar) ? r : 0.0f;
#pragma unroll
        for (int off = 32; off > 0; off >>= 1) val += __shfl_down(val, off);
        if (lane == 0) wf[wave] = val;
        __syncthreads();
        if (tid == 0) total = wf[0] + wf[1] + wf[2] + wf[3];
    }
    if (tid == 0) out[0] = s_base + 5.0f * total;
}

extern "C" void kernel_launch(void* const* d_in, const int* in_sizes, int n_in,
                              void* d_out, int out_size, void* d_ws, size_t ws_size,
                              hipStream_t stream) {
    (void)in_sizes; (void)n_in; (void)out_size; (void)ws_size;
    const float* p = (const float*)d_in[0];   // predictions
    const float* t = (const float*)d_in[1];   // targets
    char* ws = (char*)d_ws;                   // ~38 KB used
    int*   cnt  = (int*)ws;
    float* sumR = (float*)(ws + (size_t)NB * 4);
    float* noo  = (float*)(ws + (size_t)NB * 8);
    float* out  = (float*)d_out;

    yolo_k1<<<NB, 256, 0, stream>>>(p, t, cnt, sumR, noo);
    yolo_k2<<<1, 256, 0, stream>>>(cnt, sumR, noo, p, t, out);
}